// Round 3
// baseline (152.074 us; speedup 1.0000x reference)
//
#include <hip/hip_runtime.h>
#include <hip/hip_bf16.h>
#include <math.h>

// ---- problem constants (hardcoded in reference) ----
#define NMETA  4
#define NNODE  871
#define NFEAT  512
#define XDIM   (116*116)            // 13456
#define ZPLANE (NNODE*NFEAT)        // 445952
#define MT     55                   // M tiles of 16 (rows 871..879 padded)

#define NXB    175                  // xh-partial blocks
#define XROWS  77                   // x rows per xh block (175*77 = 13475 >= 13456)

// ---- workspace layout (float offsets) ----
#define WS_SPART  16                 // [220]   score sums (p*55+c)
#define WS_C1P    256                // [4*512] c1 partials (per f-slice)
#define WS_XHP    8448               // [175*512] xh partials
#define WS_V      98304              // [871]
#define WS_W1P    99328              // packed bf16 w1[512:1024] (262144 shorts)
#define WS_W2P    230400             // packed bf16 w2 (65536 shorts)
#define WS_FXHP   263168             // [175] flags
#define WS_FPACK  263344             // [20]  flags (0..15 w1p, 16..19 w2p)
#define WS_FC1    263368             // [4]   flags
#define WS_FSP    263376             // [55]  flags
#define WS_FV     263436             // [55]  flags
#define MAGICF    0x13579BDFu

typedef short v8s __attribute__((ext_vector_type(8)));
typedef float v4f __attribute__((ext_vector_type(4)));

static __device__ __forceinline__ short f2bf(float f) {
  __hip_bfloat16 h = __float2bfloat16(f);
  return *reinterpret_cast<short*>(&h);
}

static __device__ __forceinline__ unsigned ldflag(const float* ws, int off) {
  return __hip_atomic_load((const unsigned*)&ws[off], __ATOMIC_RELAXED,
                           __HIP_MEMORY_SCOPE_AGENT);
}
static __device__ __forceinline__ void stflag(float* ws, int off) {
  __builtin_amdgcn_fence(__ATOMIC_RELEASE, "agent");
  __hip_atomic_store((unsigned*)&ws[off], MAGICF, __ATOMIC_RELAXED,
                     __HIP_MEMORY_SCOPE_AGENT);
}

// ================= single fused kernel, 254 blocks x 1024 threads =================
// blk 0..54    FUSED  : z->regs, spart+flag, spin spart(55), coef, emb, spin(pack16+c1 4),
//                       E1, relu+c1, spin(w2p 4), H2, rowdot, v+flag; blk0: spin v(55), loss
// blk 55..229  XHP    : 77 x-rows GEMV partial + flag
// blk 230..233 C1     : spin xhp(175), reduce+GEMV f-slice, c1 partial + flag
// blk 234..253 PACK   : w1p/w2p bf16 repack + flag
// Co-residency: 254 blocks <= 256 CUs, 16 waves/block, <=128 VGPR, 37.5 KB LDS
// -> every block resident immediately -> flag spins cannot deadlock.
__global__ __launch_bounds__(1024) void k_all(const float* __restrict__ z,
                                              const float* __restrict__ x,
                                              const float* __restrict__ W,
                                              const float* __restrict__ b,
                                              const float* __restrict__ q,
                                              const float* __restrict__ xpw,
                                              const float* __restrict__ xpb,
                                              const float* __restrict__ w1,
                                              const float* __restrict__ b1,
                                              const float* __restrict__ w2,
                                              const float* __restrict__ b2,
                                              const float* __restrict__ w3,
                                              const float* __restrict__ b3,
                                              float* __restrict__ ws,
                                              float* __restrict__ out,
                                              short* __restrict__ w1p,
                                              short* __restrict__ w2p) {
  __shared__ __align__(16) char pool[37376];
  const int blk = blockIdx.x;
  const int tid = threadIdx.x;

  if (blk < MT) {
    // ---------------- FUSED M-tile block ----------------
    short* embs = (short*)pool;                 // 16384 B  [64 koct][16 m][8] swizzled
    short* h2a  = (short*)(pool + 16384);       // 16384 B
    float* cs   = (float*)(pool + 32768);       // 512
    float* spl  = (float*)(pool + 34816);       // 220
    float* sred = (float*)(pool + 35712);       // [16][4]
    float* cf   = (float*)(pool + 35968);       // 4
    float* vred = (float*)(pool + 36000);       // [16][17]
    float* wred = (float*)(pool + 37088);       // [16][2]

    const int r0 = blk * 16;
    const int oc = tid & 63;                    // k-octet 0..63 (== lane)
    const int row = tid >> 6;                   // 0..15 (== wave)
    const int gr = r0 + row;
    const bool valid = gr < NNODE;

    // load z (4 planes x 8 floats) + q (8 floats) + W,b into regs
    const float4* z4 = (const float4*)z;
    const float4* q4 = (const float4*)q;
    float4 za0, za1, zb0, zb1, zc0, zc1, zd0, zd1, qa, qb;
    float wi = 0.f, bi = 0.f;
    const int zi = gr * 128 + oc * 2;
    if (valid) {
      za0 = z4[zi];                 za1 = z4[zi + 1];
      zb0 = z4[NNODE*128 + zi];     zb1 = z4[NNODE*128 + zi + 1];
      zc0 = z4[2*NNODE*128 + zi];   zc1 = z4[2*NNODE*128 + zi + 1];
      zd0 = z4[3*NNODE*128 + zi];   zd1 = z4[3*NNODE*128 + zi + 1];
      qa  = q4[gr * 128 + oc * 2];  qb  = q4[gr * 128 + oc * 2 + 1];
      wi = W[gr]; bi = b[gr];
    } else {
      za0 = za1 = zb0 = zb1 = zc0 = zc1 = zd0 = zd1 = (float4){0,0,0,0};
      qa = qb = (float4){0,0,0,0};
    }

    // spart: per-plane tanh-dot for this thread's 8 features, wave-reduce over oc
    auto dot8 = [&](const float4& u0, const float4& u1) -> float {
      return tanhf(wi*u0.x + bi)*qa.x + tanhf(wi*u0.y + bi)*qa.y
           + tanhf(wi*u0.z + bi)*qa.z + tanhf(wi*u0.w + bi)*qa.w
           + tanhf(wi*u1.x + bi)*qb.x + tanhf(wi*u1.y + bi)*qb.y
           + tanhf(wi*u1.z + bi)*qb.z + tanhf(wi*u1.w + bi)*qb.w;
    };
    float sp0 = valid ? dot8(za0, za1) : 0.f;
    float sp1 = valid ? dot8(zb0, zb1) : 0.f;
    float sp2 = valid ? dot8(zc0, zc1) : 0.f;
    float sp3 = valid ? dot8(zd0, zd1) : 0.f;
#pragma unroll
    for (int m = 1; m < 64; m <<= 1) {
      sp0 += __shfl_xor(sp0, m); sp1 += __shfl_xor(sp1, m);
      sp2 += __shfl_xor(sp2, m); sp3 += __shfl_xor(sp3, m);
    }
    if (oc == 0) {
      sred[row*4+0] = sp0; sred[row*4+1] = sp1;
      sred[row*4+2] = sp2; sred[row*4+3] = sp3;
    }
    __syncthreads();
    if (tid < 4) {
      float s = 0.f;
#pragma unroll
      for (int r = 0; r < 16; ++r) s += sred[r*4 + tid];
      ws[WS_SPART + tid * 55 + blk] = s;        // raw sum over this block's rows
    }
    __syncthreads();                            // drain stores (vmcnt0 before barrier)
    if (tid == 0) stflag(ws, WS_FSP + blk);

    // spin: all 55 spart flags -> coef
    for (;;) {
      int ok = 1;
      if (tid < 55) ok = (ldflag(ws, WS_FSP + tid) == MAGICF);
      if (__syncthreads_and(ok)) break;
      __builtin_amdgcn_s_sleep(2);
    }
    __builtin_amdgcn_fence(__ATOMIC_ACQUIRE, "agent");
    if (tid < 220) spl[tid] = ws[WS_SPART + tid];
    __syncthreads();
    if (tid == 0) {
      float sv[NMETA], sum = 0.f;
#pragma unroll
      for (int p = 0; p < NMETA; ++p) {
        float s = 0.f;
        for (int c = 0; c < MT; ++c) s += spl[p * 55 + c];
        sv[p] = s / (float)NNODE;
        sum += sv[p];
      }
      float m = -1e30f;
#pragma unroll
      for (int p = 0; p < NMETA; ++p) { sv[p] = sv[p] / sum; m = fmaxf(m, sv[p]); }
      float es = 0.f;
#pragma unroll
      for (int p = 0; p < NMETA; ++p) { sv[p] = expf(sv[p] - m); es += sv[p]; }
#pragma unroll
      for (int p = 0; p < NMETA; ++p) cf[p] = 1.f + sv[p] / es;
    }
    __syncthreads();
    const float c0 = cf[0], c1c = cf[1], c2 = cf[2], c3 = cf[3];

    // emb from regs -> out (fp32) + embs (bf16 A-fragment)
    {
      const int slot = oc * 16 + (row ^ (oc & 15));
      v8s h;
      if (valid) {
        float4 r0v, r1v;
        r0v.x = c0*za0.x + c1c*zb0.x + c2*zc0.x + c3*zd0.x;
        r0v.y = c0*za0.y + c1c*zb0.y + c2*zc0.y + c3*zd0.y;
        r0v.z = c0*za0.z + c1c*zb0.z + c2*zc0.z + c3*zd0.z;
        r0v.w = c0*za0.w + c1c*zb0.w + c2*zc0.w + c3*zd0.w;
        r1v.x = c0*za1.x + c1c*zb1.x + c2*zc1.x + c3*zd1.x;
        r1v.y = c0*za1.y + c1c*zb1.y + c2*zc1.y + c3*zd1.y;
        r1v.z = c0*za1.z + c1c*zb1.z + c2*zc1.z + c3*zd1.z;
        r1v.w = c0*za1.w + c1c*zb1.w + c2*zc1.w + c3*zd1.w;
        ((float4*)out)[zi] = r0v;
        ((float4*)out)[zi + 1] = r1v;
        h[0] = f2bf(r0v.x); h[1] = f2bf(r0v.y); h[2] = f2bf(r0v.z); h[3] = f2bf(r0v.w);
        h[4] = f2bf(r1v.x); h[5] = f2bf(r1v.y); h[6] = f2bf(r1v.z); h[7] = f2bf(r1v.w);
      } else {
        h = (v8s){0,0,0,0,0,0,0,0};
      }
      *(v8s*)(embs + slot * 8) = h;
    }
    __syncthreads();

    // spin: w1p pack (16) + c1 (4)
    for (;;) {
      int ok = 1;
      if (tid < 16) ok = (ldflag(ws, WS_FPACK + tid) == MAGICF);
      else if (tid < 20) ok = (ldflag(ws, WS_FC1 + (tid - 16)) == MAGICF);
      if (__syncthreads_and(ok)) break;
      __builtin_amdgcn_s_sleep(2);
    }
    __builtin_amdgcn_fence(__ATOMIC_ACQUIRE, "agent");
    if (tid < 512) {
      float a = 0.f;
#pragma unroll
      for (int k = 0; k < 4; ++k) a += ws[WS_C1P + k * 512 + tid];
      cs[tid] = a;
    }
    __syncthreads();

    // E1: wave w (0..15) -> 2 n-tiles (cols w*32..w*32+31)
    const int lane = tid & 63, w = tid >> 6;
    const int n15 = lane & 15, quad = lane >> 4;
    v4f e[2];
#pragma unroll
    for (int ct = 0; ct < 2; ++ct) e[ct] = (v4f){0.f, 0.f, 0.f, 0.f};
#pragma unroll
    for (int kb = 0; kb < 16; ++kb) {
      const int koct = kb * 4 + quad;
      v8s a = *(const v8s*)(embs + (koct * 16 + (n15 ^ (koct & 15))) * 8);
      const short* B = w1p + kb * 16384 + w * 1024 + quad * 128 + n15 * 8;
#pragma unroll
      for (int ct = 0; ct < 2; ++ct) {
        v8s bb = *(const v8s*)(B + ct * 512);
        e[ct] = __builtin_amdgcn_mfma_f32_16x16x32_bf16(a, bb, e[ct], 0, 0, 0);
      }
    }
#pragma unroll
    for (int ct = 0; ct < 2; ++ct) {
      const int col = w * 32 + ct * 16 + n15;
      const int koct = col >> 3, j = col & 7;
#pragma unroll
      for (int r = 0; r < 4; ++r) {
        const int m = quad * 4 + r;
        h2a[(koct * 16 + (m ^ (koct & 15))) * 8 + j] = f2bf(fmaxf(e[ct][r] + cs[col], 0.f));
      }
    }
    __syncthreads();

    // spin: w2p pack (4) -- almost certainly already done
    for (;;) {
      int ok = 1;
      if (tid < 4) ok = (ldflag(ws, WS_FPACK + 16 + tid) == MAGICF);
      if (__syncthreads_and(ok)) break;
      __builtin_amdgcn_s_sleep(2);
    }
    __builtin_amdgcn_fence(__ATOMIC_ACQUIRE, "agent");

    // H2: wave w -> 1 n-tile (cols w*16..w*16+15); fused rowdot
    v4f g = (v4f){0.f, 0.f, 0.f, 0.f};
#pragma unroll
    for (int kb = 0; kb < 16; ++kb) {
      const int koct = kb * 4 + quad;
      v8s a = *(const v8s*)(h2a + (koct * 16 + (n15 ^ (koct & 15))) * 8);
      v8s bb = *(const v8s*)(w2p + kb * 8192 + w * 512 + quad * 128 + n15 * 8);
      g = __builtin_amdgcn_mfma_f32_16x16x32_bf16(a, bb, g, 0, 0, 0);
    }
    {
      const int col = w * 16 + n15;
      const float b2v = b2[col], w3v = w3[col];
#pragma unroll
      for (int r = 0; r < 4; ++r) {
        float s = fmaxf(g[r] + b2v, 0.f) * w3v;
        s += __shfl_xor(s, 1);
        s += __shfl_xor(s, 2);
        s += __shfl_xor(s, 4);
        s += __shfl_xor(s, 8);
        if (n15 == 0) vred[(quad * 4 + r) * 17 + w] = s;
      }
    }
    __syncthreads();
    if (tid < 16) {
      float acc = 0.f;
#pragma unroll
      for (int ww = 0; ww < 16; ++ww) acc += vred[tid * 17 + ww];
      const int grow = r0 + tid;
      if (grow < NNODE) ws[WS_V + grow] = acc;  // single writer per row
    }
    __syncthreads();
    if (tid == 0) stflag(ws, WS_FV + blk);

    // block 0: final loss
    if (blk == 0) {
      for (;;) {
        int ok = 1;
        if (tid < 55) ok = (ldflag(ws, WS_FV + tid) == MAGICF);
        if (__syncthreads_and(ok)) break;
        __builtin_amdgcn_s_sleep(2);
      }
      __builtin_amdgcn_fence(__ATOMIC_ACQUIRE, "agent");
      const float bias = b3[0];
      float s0 = 0.f, s1 = 0.f;
      if (tid < NNODE) {
        float xv = ws[WS_V + tid] + bias;
        s0 = xv; s1 = expf(xv);
      }
#pragma unroll
      for (int m = 1; m < 64; m <<= 1) { s0 += __shfl_xor(s0, m); s1 += __shfl_xor(s1, m); }
      if (lane == 0) { wred[w * 2] = s0; wred[w * 2 + 1] = s1; }
      __syncthreads();
      if (tid == 0) {
        float t0 = 0.f, t1 = 0.f;
#pragma unroll
        for (int ww = 0; ww < 16; ++ww) { t0 += wred[ww * 2]; t1 += wred[ww * 2 + 1]; }
        float m0 = t0 / (float)NNODE;
        float m1 = t1 / (float)NNODE;
        float mi = m0 - logf(m1 + 1e-8f);
        out[ZPLANE] = fmaxf(mi, 0.f) + 0.1f;   // sum(softmax)==1 -> gamma term = 0.1
      }
    }
  } else if (blk < MT + NXB) {
    // ---------------- XHP block: xhp[xb][f] = sum_{d in span} x[d]*xp_w[d,f] ----------------
    const int xb = blk - MT;
    const int d0 = xb * XROWS;
    const int rows = min(XROWS, XDIM - d0);
    float* xs = (float*)pool;                   // 77
    float4* redx = (float4*)(pool + 320);       // [7][128]
    if (tid < rows) xs[tid] = x[d0 + tid];
    __syncthreads();
    const int f4 = tid & 127;
    const int rp = tid >> 7;                    // 0..7
    float4 acc = {0.f, 0.f, 0.f, 0.f};
    const float4* xp4 = (const float4*)xpw;
    for (int r = rp; r < rows; r += 8) {
      const float xv = xs[r];
      const float4 wv = xp4[(size_t)(d0 + r) * 128 + f4];
      acc.x += xv * wv.x; acc.y += xv * wv.y; acc.z += xv * wv.z; acc.w += xv * wv.w;
    }
    if (rp) redx[(rp - 1) * 128 + f4] = acc;
    __syncthreads();
    if (!rp) {
#pragma unroll
      for (int g = 0; g < 7; ++g) {
        float4 t = redx[g * 128 + f4];
        acc.x += t.x; acc.y += t.y; acc.z += t.z; acc.w += t.w;
      }
      ((float4*)(ws + WS_XHP + (size_t)xb * 512))[f4] = acc;
    }
    __syncthreads();
    if (tid == 0) stflag(ws, WS_FXHP + xb);
  } else if (blk < MT + NXB + 4) {
    // ---------------- C1 block: f-slice [bk*128, bk*128+128) ----------------
    const int bk = blk - (MT + NXB);
    float* xh = (float*)pool;                   // 128
    float* redr = (float*)(pool + 512);         // 1024
    float4* redg = (float4*)(pool + 4608);      // [7][128]
    for (;;) {
      int ok = 1;
      if (tid < NXB) ok = (ldflag(ws, WS_FXHP + tid) == MAGICF);
      if (__syncthreads_and(ok)) break;
      __builtin_amdgcn_s_sleep(2);
    }
    __builtin_amdgcn_fence(__ATOMIC_ACQUIRE, "agent");
    const int f = tid & 127;
    const int part = tid >> 7;                  // 0..7
    {
      float s = 0.f;
      for (int p = part; p < NXB; p += 8) s += ws[WS_XHP + (size_t)p * 512 + bk * 128 + f];
      redr[tid] = s;
    }
    __syncthreads();
    if (tid < 128) {
      float t = xpb[bk * 128 + tid];
#pragma unroll
      for (int g = 0; g < 8; ++g) t += redr[g * 128 + tid];
      xh[tid] = t;
    }
    __syncthreads();
    // GEMV: c1p[bk][j] = sum_{f in slice} xh[f] * w1[f, j]
    const int j4 = tid & 127;
    const int fg = tid >> 7;                    // 0..7 (16 f each)
    float4 acc = {0.f, 0.f, 0.f, 0.f};
    const float4* w14 = (const float4*)w1;
#pragma unroll
    for (int ff = 0; ff < 16; ++ff) {
      const int fr = bk * 128 + fg * 16 + ff;
      const float xv = xh[fg * 16 + ff];
      const float4 wv = w14[(size_t)fr * 128 + j4];
      acc.x += xv * wv.x; acc.y += xv * wv.y; acc.z += xv * wv.z; acc.w += xv * wv.w;
    }
    if (fg) redg[(fg - 1) * 128 + j4] = acc;
    __syncthreads();
    if (!fg) {
#pragma unroll
      for (int g = 0; g < 7; ++g) {
        float4 t = redg[g * 128 + j4];
        acc.x += t.x; acc.y += t.y; acc.z += t.z; acc.w += t.w;
      }
      if (bk == 0) {
        acc.x += b1[j4 * 4 + 0]; acc.y += b1[j4 * 4 + 1];
        acc.z += b1[j4 * 4 + 2]; acc.w += b1[j4 * 4 + 3];
      }
      ((float4*)(ws + WS_C1P + (size_t)bk * 512))[j4] = acc;
    }
    __syncthreads();
    if (tid == 0) stflag(ws, WS_FC1 + bk);
  } else {
    // ---------------- PACK block: bf16 repack, coalesced source reads ----------------
    const int pb = blk - (MT + NXB + 4);
    if (pb < 16) {
      const int s0 = pb * 16384;
#pragma unroll
      for (int it = 0; it < 16; ++it) {
        const int s = s0 + it * 1024 + tid;
        const int k = s >> 9, n = s & 511;
        const int t = (k >> 5) * 16384 + (n >> 4) * 512 + ((k >> 3) & 3) * 128
                    + (n & 15) * 8 + (k & 7);
        w1p[t] = f2bf(w1[(size_t)(512 + k) * 512 + n]);
      }
    } else {
      const int o0 = (pb - 16) * 16384;
#pragma unroll
      for (int it = 0; it < 16; ++it) {
        const int o = o0 + it * 1024 + tid;
        const int k = o >> 8, n = o & 255;
        const int t = (k >> 5) * 8192 + (n >> 4) * 512 + ((k >> 3) & 3) * 128
                    + (n & 15) * 8 + (k & 7);
        w2p[t] = f2bf(w2[(size_t)k * 256 + n]);
      }
    }
    __syncthreads();
    if (tid == 0) stflag(ws, WS_FPACK + pb);
  }
}

extern "C" void kernel_launch(void* const* d_in, const int* in_sizes, int n_in,
                              void* d_out, int out_size, void* d_ws, size_t ws_size,
                              hipStream_t stream) {
  const float* z   = (const float*)d_in[0];
  const float* x   = (const float*)d_in[1];
  const float* W   = (const float*)d_in[2];
  const float* b   = (const float*)d_in[3];
  const float* q   = (const float*)d_in[4];
  const float* xpw = (const float*)d_in[5];
  const float* xpb = (const float*)d_in[6];
  const float* w1  = (const float*)d_in[7];
  const float* b1  = (const float*)d_in[8];
  const float* w2  = (const float*)d_in[9];
  const float* b2  = (const float*)d_in[10];
  const float* w3  = (const float*)d_in[11];
  const float* b3  = (const float*)d_in[12];
  // d_in[13] (perm) unused: xh identical per row => permutation invariant under mean(exp(.)).
  float* out = (float*)d_out;
  float* ws  = (float*)d_ws;

  short* w1p = (short*)(ws + WS_W1P);
  short* w2p = (short*)(ws + WS_W2P);

  k_all<<<MT + NXB + 4 + 20, 1024, 0, stream>>>(z, x, W, b, q, xpw, xpb, w1, b1,
                                                w2, b2, w3, b3, ws, out, w1p, w2p);
}

// Round 4
// 143.806 us; speedup vs baseline: 1.0575x; 1.0575x over previous
//
#include <hip/hip_runtime.h>
#include <hip/hip_bf16.h>
#include <math.h>

// ---- problem constants (hardcoded in reference) ----
#define NMETA  4
#define NNODE  871
#define NFEAT  512
#define XDIM   (116*116)            // 13456
#define ZPLANE (NNODE*NFEAT)        // 445952
#define MT     55                   // M tiles of 16 (rows 871..879 padded)

#define NXB    254                  // xh-partial blocks
#define XROWS  53                   // x rows per xh block (254*53 = 13462 >= 13456)

// ---- workspace layout (float offsets) ----
#define WS_CNT    12                 // [1]   completion counter (zeroed by k_front)
#define WS_SPART  16                 // [220] score sums (p*55 + mtile)
#define WS_C1P    256                // [4*512] c1 partials (per 128-f slice)
#define WS_XHP    2560               // [254*512] xh partials
#define WS_V      132608             // [871]
#define WS_W1P    133504             // packed bf16 w1[512:1024] (262144 shorts)
#define WS_W2P    264576             // packed bf16 w2 (65536 shorts)
#define WS_FXHP   297344             // [254] xhp-done flags
#define MAGICF    0x13579BDFu

typedef short v8s __attribute__((ext_vector_type(8)));
typedef float v4f __attribute__((ext_vector_type(4)));

static __device__ __forceinline__ short f2bf(float f) {
  __hip_bfloat16 h = __float2bfloat16(f);
  return *reinterpret_cast<short*>(&h);
}

static __device__ __forceinline__ unsigned ldflag(const float* ws, int off) {
  return __hip_atomic_load((const unsigned*)&ws[off], __ATOMIC_RELAXED,
                           __HIP_MEMORY_SCOPE_AGENT);
}
static __device__ __forceinline__ void stflag(float* ws, int off) {
  __builtin_amdgcn_fence(__ATOMIC_RELEASE, "agent");
  __hip_atomic_store((unsigned*)&ws[off], MAGICF, __ATOMIC_RELAXED,
                     __HIP_MEMORY_SCOPE_AGENT);
}

// ============ k_front (333 blocks x 1024 thr):
//   0..253   XHP   : 53 x-rows GEMV partial, 16 waves/block for MLP, + flag
//   254..308 SPART : 16 z-rows x 4 planes from regs, tanh-dot, shfl reduce
//   309..328 PACK  : w1p/w2p bf16 repack (coalesced reads)
//   329..332 C1    : spin xhp(254) -> reduce + GEMV 128-f slice -> c1 partial
// 333 blocks x 1024 thr: <=2 blocks/CU -> all co-resident; only C1 spins,
// and C1 depends only on non-spinning XHP blocks -> no deadlock.
__global__ __launch_bounds__(1024) void k_front(const float* __restrict__ x,
                                                const float* __restrict__ xpw,
                                                const float* __restrict__ w1,
                                                const float* __restrict__ w2,
                                                const float* __restrict__ z,
                                                const float* __restrict__ W,
                                                const float* __restrict__ b,
                                                const float* __restrict__ q,
                                                const float* __restrict__ xpb,
                                                const float* __restrict__ b1,
                                                float* __restrict__ ws,
                                                short* __restrict__ w1p,
                                                short* __restrict__ w2p) {
  const int blk = blockIdx.x;
  const int tid = threadIdx.x;

  if (blk < NXB) {
    // ---------------- XHP: xhp[blk][f] = sum_{d in span} x[d]*xp_w[d,f] ----------------
    const int d0 = blk * XROWS;
    const int rows = min(XROWS, XDIM - d0);
    __shared__ float xs[XROWS];
    __shared__ float4 redx[7][128];
    if (tid < rows) xs[tid] = x[d0 + tid];
    __syncthreads();
    const int f4 = tid & 127;
    const int g = tid >> 7;                    // 0..7
    float4 acc = {0.f, 0.f, 0.f, 0.f};
    const float4* xp4 = (const float4*)xpw;
    for (int r = g; r < rows; r += 8) {        // <=7 independent loads in flight
      const float xv = xs[r];
      const float4 wv = xp4[(size_t)(d0 + r) * 128 + f4];
      acc.x += xv * wv.x; acc.y += xv * wv.y; acc.z += xv * wv.z; acc.w += xv * wv.w;
    }
    if (g) redx[g - 1][f4] = acc;
    __syncthreads();
    if (!g) {
#pragma unroll
      for (int k = 0; k < 7; ++k) {
        float4 t = redx[k][f4];
        acc.x += t.x; acc.y += t.y; acc.z += t.z; acc.w += t.w;
      }
      ((float4*)(ws + WS_XHP + (size_t)blk * 512))[f4] = acc;
    }
    __syncthreads();                           // drain stores before flag
    if (tid == 0) stflag(ws, WS_FXHP + blk);
  } else if (blk < NXB + MT) {
    // ---------------- SPART: tanh-dot for rows [sb*16, sb*16+16), all 4 planes ----------------
    const int sb = blk - NXB;
    const int row = tid >> 6;                  // 0..15
    const int oc = tid & 63;                   // feature octet
    const int gr = sb * 16 + row;
    const bool valid = gr < NNODE;
    const float4* z4 = (const float4*)z;
    const float4* q4 = (const float4*)q;
    float4 za0, za1, zb0, zb1, zc0, zc1, zd0, zd1, qa, qb;
    float wi = 0.f, bi = 0.f;
    za0 = za1 = zb0 = zb1 = zc0 = zc1 = zd0 = zd1 = (float4){0,0,0,0};
    qa = qb = (float4){0,0,0,0};
    const int zi = gr * 128 + oc * 2;
    if (valid) {
      za0 = z4[zi];                 za1 = z4[zi + 1];
      zb0 = z4[NNODE*128 + zi];     zb1 = z4[NNODE*128 + zi + 1];
      zc0 = z4[2*NNODE*128 + zi];   zc1 = z4[2*NNODE*128 + zi + 1];
      zd0 = z4[3*NNODE*128 + zi];   zd1 = z4[3*NNODE*128 + zi + 1];
      qa  = q4[zi];                 qb  = q4[zi + 1];
      wi = W[gr]; bi = b[gr];
    }
    auto dot8 = [&](const float4& u0, const float4& u1) -> float {
      return tanhf(wi*u0.x + bi)*qa.x + tanhf(wi*u0.y + bi)*qa.y
           + tanhf(wi*u0.z + bi)*qa.z + tanhf(wi*u0.w + bi)*qa.w
           + tanhf(wi*u1.x + bi)*qb.x + tanhf(wi*u1.y + bi)*qb.y
           + tanhf(wi*u1.z + bi)*qb.z + tanhf(wi*u1.w + bi)*qb.w;
    };
    float sp0 = valid ? dot8(za0, za1) : 0.f;
    float sp1 = valid ? dot8(zb0, zb1) : 0.f;
    float sp2 = valid ? dot8(zc0, zc1) : 0.f;
    float sp3 = valid ? dot8(zd0, zd1) : 0.f;
#pragma unroll
    for (int m = 1; m < 64; m <<= 1) {
      sp0 += __shfl_xor(sp0, m); sp1 += __shfl_xor(sp1, m);
      sp2 += __shfl_xor(sp2, m); sp3 += __shfl_xor(sp3, m);
    }
    __shared__ float sred[16][4];
    if (oc == 0) {
      sred[row][0] = sp0; sred[row][1] = sp1;
      sred[row][2] = sp2; sred[row][3] = sp3;
    }
    __syncthreads();
    if (tid < 4) {
      float s = 0.f;
#pragma unroll
      for (int r = 0; r < 16; ++r) s += sred[r][tid];
      ws[WS_SPART + tid * 55 + sb] = s;        // raw sum over this tile's rows
    }
  } else if (blk < NXB + MT + 20) {
    // ---------------- PACK: bf16 repack, coalesced source reads ----------------
    const int pb = blk - (NXB + MT);
    if (pb < 16) {
      const int s0 = pb * 16384;
#pragma unroll
      for (int it = 0; it < 16; ++it) {
        const int s = s0 + it * 1024 + tid;
        const int k = s >> 9, n = s & 511;
        const int t = (k >> 5) * 16384 + (n >> 4) * 512 + ((k >> 3) & 3) * 128
                    + (n & 15) * 8 + (k & 7);
        w1p[t] = f2bf(w1[(size_t)(512 + k) * 512 + n]);
      }
    } else {
      const int o0 = (pb - 16) * 16384;
#pragma unroll
      for (int it = 0; it < 16; ++it) {
        const int o = o0 + it * 1024 + tid;
        const int k = o >> 8, n = o & 255;
        const int t = (k >> 5) * 8192 + (n >> 4) * 512 + ((k >> 3) & 3) * 128
                    + (n & 15) * 8 + (k & 7);
        w2p[t] = f2bf(w2[(size_t)k * 256 + n]);
      }
    }
  } else {
    // ---------------- C1: f-slice [bk*128, bk*128+128) ----------------
    const int bk = blk - (NXB + MT + 20);
    __shared__ float xh[128];
    __shared__ float redr[1024];
    __shared__ float4 redg[7][128];
    if (tid == 1023) *(unsigned*)&ws[WS_CNT] = 0u;   // consumed by k_fused (next launch)
    for (;;) {
      int ok = 1;
      if (tid < NXB) ok = (ldflag(ws, WS_FXHP + tid) == MAGICF);
      if (__syncthreads_and(ok)) break;
      __builtin_amdgcn_s_sleep(2);
    }
    __builtin_amdgcn_fence(__ATOMIC_ACQUIRE, "agent");
    const int f = tid & 127;
    const int part = tid >> 7;                 // 0..7
    {
      float s = 0.f;
      for (int p = part; p < NXB; p += 8)
        s += ws[WS_XHP + (size_t)p * 512 + bk * 128 + f];
      redr[tid] = s;
    }
    __syncthreads();
    if (tid < 128) {
      float t = xpb[bk * 128 + tid];
#pragma unroll
      for (int g = 0; g < 8; ++g) t += redr[g * 128 + tid];
      xh[tid] = t;
    }
    __syncthreads();
    // GEMV: c1p[bk][j] = sum_{f in slice} xh[f] * w1[f, j]
    const int j4 = tid & 127;
    const int fg = tid >> 7;                   // 0..7 (16 f each)
    float4 acc = {0.f, 0.f, 0.f, 0.f};
    const float4* w14 = (const float4*)w1;
#pragma unroll
    for (int ff = 0; ff < 16; ++ff) {
      const int fr = bk * 128 + fg * 16 + ff;
      const float xv = xh[fg * 16 + ff];
      const float4 wv = w14[(size_t)fr * 128 + j4];
      acc.x += xv * wv.x; acc.y += xv * wv.y; acc.z += xv * wv.z; acc.w += xv * wv.w;
    }
    if (fg) redg[fg - 1][j4] = acc;
    __syncthreads();
    if (!fg) {
#pragma unroll
      for (int g = 0; g < 7; ++g) {
        float4 t = redg[g][j4];
        acc.x += t.x; acc.y += t.y; acc.z += t.z; acc.w += t.w;
      }
      if (bk == 0) {
        acc.x += b1[j4 * 4 + 0]; acc.y += b1[j4 * 4 + 1];
        acc.z += b1[j4 * 4 + 2]; acc.w += b1[j4 * 4 + 3];
      }
      ((float4*)(ws + WS_C1P + (size_t)bk * 512))[j4] = acc;
    }
  }
}

// ============ k_fused (55 blocks x 1024 thr): coef(redundant) -> emb -> E1 -> relu+c1 -> H2
//              -> rowdot -> v store -> (last block) loss
// All cross-kernel inputs (spart, c1p, w1p, w2p) are coherent via the kernel boundary:
// no flags, no fences on the critical path before the MFMA phases.
__global__ __launch_bounds__(1024) void k_fused(const float* __restrict__ z,
                                                float* __restrict__ ws,
                                                float* __restrict__ out,
                                                const short* __restrict__ w1p,
                                                const short* __restrict__ w2p,
                                                const float* __restrict__ b2,
                                                const float* __restrict__ w3,
                                                const float* __restrict__ b3) {
  __shared__ __align__(16) short embs[8192];   // [64 koct][16 m][8], swizzled
  __shared__ __align__(16) short h2a[8192];
  __shared__ float cs[512];
  __shared__ float rf0[1024], rf1[1024];
  __shared__ float vred[16][17];
  __shared__ float cf[4];
  __shared__ float svred[4];
  const int tid = threadIdx.x;
  const int r0 = blockIdx.x * 16;
  const int oc = tid & 63;                     // k-octet / lane
  const int row = tid >> 6;                    // 0..15 / wave
  const int gr = r0 + row;
  const bool valid = gr < NNODE;

  // ---- issue z loads early (latency hides under coef + cs) ----
  const float4* z4 = (const float4*)z;
  float4 za0, za1, zb0, zb1, zc0, zc1, zd0, zd1;
  za0 = za1 = zb0 = zb1 = zc0 = zc1 = zd0 = zd1 = (float4){0,0,0,0};
  const int zi = gr * 128 + oc * 2;
  if (valid) {
    za0 = z4[zi];                 za1 = z4[zi + 1];
    zb0 = z4[NNODE*128 + zi];     zb1 = z4[NNODE*128 + zi + 1];
    zc0 = z4[2*NNODE*128 + zi];   zc1 = z4[2*NNODE*128 + zi + 1];
    zd0 = z4[3*NNODE*128 + zi];   zd1 = z4[3*NNODE*128 + zi + 1];
  }

  // ---- cs: c1 = sum of 4 slice-partials ----
  if (tid < 512) {
    float a = 0.f;
#pragma unroll
    for (int k = 0; k < 4; ++k) a += ws[WS_C1P + k * 512 + tid];
    cs[tid] = a;
  }

  // ---- coef: waves 0..3 reduce one plane's 55 spart chunks, thread 0 softmaxes ----
  {
    const int w4 = tid >> 6;
    if (w4 < 4) {
      float v = (oc < 55) ? ws[WS_SPART + w4 * 55 + oc] : 0.f;
#pragma unroll
      for (int m = 1; m < 64; m <<= 1) v += __shfl_xor(v, m);
      if (oc == 0) svred[w4] = v;
    }
  }
  __syncthreads();
  if (tid == 0) {
    float sv[NMETA], sum = 0.f;
#pragma unroll
    for (int p = 0; p < NMETA; ++p) { sv[p] = svred[p] / (float)NNODE; sum += sv[p]; }
    float m = -1e30f;
#pragma unroll
    for (int p = 0; p < NMETA; ++p) { sv[p] = sv[p] / sum; m = fmaxf(m, sv[p]); }
    float es = 0.f;
#pragma unroll
    for (int p = 0; p < NMETA; ++p) { sv[p] = expf(sv[p] - m); es += sv[p]; }
#pragma unroll
    for (int p = 0; p < NMETA; ++p) cf[p] = 1.f + sv[p] / es;
  }
  __syncthreads();
  const float c0 = cf[0], c1c = cf[1], c2 = cf[2], c3 = cf[3];

  // ---- emb from regs -> out (fp32) + embs (bf16 A-fragment) ----
  {
    const int slot = oc * 16 + (row ^ (oc & 15));
    v8s h;
    if (valid) {
      float4 r0v, r1v;
      r0v.x = c0*za0.x + c1c*zb0.x + c2*zc0.x + c3*zd0.x;
      r0v.y = c0*za0.y + c1c*zb0.y + c2*zc0.y + c3*zd0.y;
      r0v.z = c0*za0.z + c1c*zb0.z + c2*zc0.z + c3*zd0.z;
      r0v.w = c0*za0.w + c1c*zb0.w + c2*zc0.w + c3*zd0.w;
      r1v.x = c0*za1.x + c1c*zb1.x + c2*zc1.x + c3*zd1.x;
      r1v.y = c0*za1.y + c1c*zb1.y + c2*zc1.y + c3*zd1.y;
      r1v.z = c0*za1.z + c1c*zb1.z + c2*zc1.z + c3*zd1.z;
      r1v.w = c0*za1.w + c1c*zb1.w + c2*zc1.w + c3*zd1.w;
      ((float4*)out)[zi] = r0v;
      ((float4*)out)[zi + 1] = r1v;
      h[0] = f2bf(r0v.x); h[1] = f2bf(r0v.y); h[2] = f2bf(r0v.z); h[3] = f2bf(r0v.w);
      h[4] = f2bf(r1v.x); h[5] = f2bf(r1v.y); h[6] = f2bf(r1v.z); h[7] = f2bf(r1v.w);
    } else {
      h = (v8s){0,0,0,0,0,0,0,0};
    }
    *(v8s*)(embs + slot * 8) = h;
  }
  __syncthreads();

  // ---- E1: wave w (0..15) -> 2 n-tiles (cols w*32..w*32+31) ----
  const int lane = tid & 63, w = tid >> 6;
  const int n15 = lane & 15, quad = lane >> 4;
  v4f e[2];
#pragma unroll
  for (int ct = 0; ct < 2; ++ct) e[ct] = (v4f){0.f, 0.f, 0.f, 0.f};
#pragma unroll
  for (int kb = 0; kb < 16; ++kb) {
    const int koct = kb * 4 + quad;
    v8s a = *(const v8s*)(embs + (koct * 16 + (n15 ^ (koct & 15))) * 8);
    const short* B = w1p + kb * 16384 + w * 1024 + quad * 128 + n15 * 8;
#pragma unroll
    for (int ct = 0; ct < 2; ++ct) {
      v8s bb = *(const v8s*)(B + ct * 512);
      e[ct] = __builtin_amdgcn_mfma_f32_16x16x32_bf16(a, bb, e[ct], 0, 0, 0);
    }
  }
#pragma unroll
  for (int ct = 0; ct < 2; ++ct) {
    const int col = w * 32 + ct * 16 + n15;
    const int koct = col >> 3, j = col & 7;
#pragma unroll
    for (int r = 0; r < 4; ++r) {
      const int m = quad * 4 + r;
      h2a[(koct * 16 + (m ^ (koct & 15))) * 8 + j] = f2bf(fmaxf(e[ct][r] + cs[col], 0.f));
    }
  }
  __syncthreads();

  // ---- H2: wave w -> 1 n-tile (cols w*16..w*16+15); fused rowdot ----
  v4f g = (v4f){0.f, 0.f, 0.f, 0.f};
#pragma unroll
  for (int kb = 0; kb < 16; ++kb) {
    const int koct = kb * 4 + quad;
    v8s a = *(const v8s*)(h2a + (koct * 16 + (n15 ^ (koct & 15))) * 8);
    v8s bb = *(const v8s*)(w2p + kb * 8192 + w * 512 + quad * 128 + n15 * 8);
    g = __builtin_amdgcn_mfma_f32_16x16x32_bf16(a, bb, g, 0, 0, 0);
  }
  {
    const int col = w * 16 + n15;
    const float b2v = b2[col], w3v = w3[col];
#pragma unroll
    for (int r = 0; r < 4; ++r) {
      float s = fmaxf(g[r] + b2v, 0.f) * w3v;
      s += __shfl_xor(s, 1);
      s += __shfl_xor(s, 2);
      s += __shfl_xor(s, 4);
      s += __shfl_xor(s, 8);
      if (n15 == 0) vred[quad * 4 + r][w] = s;
    }
  }
  __syncthreads();
  if (tid < 16) {
    float acc = 0.f;
#pragma unroll
    for (int ww = 0; ww < 16; ++ww) acc += vred[tid][ww];
    const int grow = r0 + tid;
    if (grow < NNODE) ws[WS_V + grow] = acc;   // single writer per row
  }

  // ---- last-block final loss ----
  __shared__ unsigned last;
  __syncthreads();
  if (tid == 0) {
    __threadfence();                           // release v stores before counting
    unsigned old = atomicAdd((unsigned int*)&ws[WS_CNT], 1u);
    last = (old == MT - 1) ? 1u : 0u;
  }
  __syncthreads();
  if (last) {
    __builtin_amdgcn_fence(__ATOMIC_ACQUIRE, "agent");   // see other blocks' v stores
    const float bias = b3[0];
    float s0 = 0.f, s1 = 0.f;
    for (int i = tid; i < NNODE; i += 1024) {
      float xv = ws[WS_V + i] + bias;
      s0 += xv;
      s1 += expf(xv);
    }
    rf0[tid] = s0; rf1[tid] = s1;
    __syncthreads();
    for (int s = 512; s > 0; s >>= 1) {
      if (tid < s) { rf0[tid] += rf0[tid + s]; rf1[tid] += rf1[tid + s]; }
      __syncthreads();
    }
    if (tid == 0) {
      float m0 = rf0[0] / (float)NNODE;
      float m1 = rf1[0] / (float)NNODE;
      float mi = m0 - logf(m1 + 1e-8f);
      out[ZPLANE] = fmaxf(mi, 0.f) + 0.1f;     // sum(softmax)==1 -> gamma term = 0.1
    }
  }
}

extern "C" void kernel_launch(void* const* d_in, const int* in_sizes, int n_in,
                              void* d_out, int out_size, void* d_ws, size_t ws_size,
                              hipStream_t stream) {
  const float* z   = (const float*)d_in[0];
  const float* x   = (const float*)d_in[1];
  const float* W   = (const float*)d_in[2];
  const float* b   = (const float*)d_in[3];
  const float* q   = (const float*)d_in[4];
  const float* xpw = (const float*)d_in[5];
  const float* xpb = (const float*)d_in[6];
  const float* w1  = (const float*)d_in[7];
  const float* b1  = (const float*)d_in[8];
  const float* w2  = (const float*)d_in[9];
  const float* b2  = (const float*)d_in[10];
  const float* w3  = (const float*)d_in[11];
  const float* b3  = (const float*)d_in[12];
  // d_in[13] (perm) unused: xh identical per row => permutation invariant under mean(exp(.)).
  float* out = (float*)d_out;
  float* ws  = (float*)d_ws;

  short* w1p = (short*)(ws + WS_W1P);
  short* w2p = (short*)(ws + WS_W2P);

  k_front<<<NXB + MT + 20 + 4, 1024, 0, stream>>>(x, xpw, w1, w2, z, W, b, q,
                                                  xpb, b1, ws, w1p, w2p);
  k_fused<<<MT, 1024, 0, stream>>>(z, ws, out, w1p, w2p, b2, w3, b3);
}

// Round 5
// 139.909 us; speedup vs baseline: 1.0870x; 1.0279x over previous
//
#include <hip/hip_runtime.h>
#include <hip/hip_bf16.h>
#include <math.h>

// ---- problem constants (hardcoded in reference) ----
#define NMETA  4
#define NNODE  871
#define NFEAT  512
#define XDIM   (116*116)            // 13456
#define ZPLANE (NNODE*NFEAT)        // 445952
#define MT     55                   // M tiles of 16 (rows 871..879 padded)

#define NXB    254                  // xh-partial blocks
#define XROWS  53                   // x rows per xh block (254*53 = 13462 >= 13456)

// ---- workspace layout (float offsets) ----
#define WS_CNT    12                 // [1]   completion counter (zeroed by k_mid)
#define WS_SPART  16                 // [220] score sums (p*55 + mtile)
#define WS_C1P    256                // [4*512] c1 partials (per 128-f slice)
#define WS_XHP    2560               // [254*512] xh partials
#define WS_V      132608             // [871]
#define WS_W1P    133504             // packed bf16 w1[512:1024] (262144 shorts)
#define WS_W2P    264576             // packed bf16 w2 (65536 shorts)

typedef short v8s __attribute__((ext_vector_type(8)));
typedef float v4f __attribute__((ext_vector_type(4)));

static __device__ __forceinline__ short f2bf(float f) {
  __hip_bfloat16 h = __float2bfloat16(f);
  return *reinterpret_cast<short*>(&h);
}

// ============ k_front (329 blocks x 1024 thr) — pure producers, NO fences/flags:
//   0..253   XHP   : 53 x-rows GEMV partial
//   254..308 SPART : 16 z-rows x 4 planes from regs, tanh-dot, shfl reduce
//   309..328 PACK  : w1p/w2p bf16 repack (coalesced source reads)
// Coherence with consumers is provided by the kernel boundary (dispatch-level
// release/acquire) — per-block agent fences (buffer_wbl2/inv) were the R2-R4
// regression and are gone.
__global__ __launch_bounds__(1024) void k_front(const float* __restrict__ x,
                                                const float* __restrict__ xpw,
                                                const float* __restrict__ w1,
                                                const float* __restrict__ w2,
                                                const float* __restrict__ z,
                                                const float* __restrict__ W,
                                                const float* __restrict__ b,
                                                const float* __restrict__ q,
                                                float* __restrict__ ws,
                                                short* __restrict__ w1p,
                                                short* __restrict__ w2p) {
  const int blk = blockIdx.x;
  const int tid = threadIdx.x;

  if (blk < NXB) {
    // ---------------- XHP: xhp[blk][f] = sum_{d in span} x[d]*xp_w[d,f] ----------------
    const int d0 = blk * XROWS;
    const int rows = min(XROWS, XDIM - d0);
    __shared__ float xs[XROWS];
    __shared__ float4 redx[7][128];
    if (tid < rows) xs[tid] = x[d0 + tid];
    __syncthreads();
    const int f4 = tid & 127;
    const int g = tid >> 7;                    // 0..7
    float4 acc = {0.f, 0.f, 0.f, 0.f};
    const float4* xp4 = (const float4*)xpw;
    for (int r = g; r < rows; r += 8) {        // <=7 independent loads in flight
      const float xv = xs[r];
      const float4 wv = xp4[(size_t)(d0 + r) * 128 + f4];
      acc.x += xv * wv.x; acc.y += xv * wv.y; acc.z += xv * wv.z; acc.w += xv * wv.w;
    }
    if (g) redx[g - 1][f4] = acc;
    __syncthreads();
    if (!g) {
#pragma unroll
      for (int k = 0; k < 7; ++k) {
        float4 t = redx[k][f4];
        acc.x += t.x; acc.y += t.y; acc.z += t.z; acc.w += t.w;
      }
      ((float4*)(ws + WS_XHP + (size_t)blk * 512))[f4] = acc;
    }
  } else if (blk < NXB + MT) {
    // ---------------- SPART: tanh-dot for rows [sb*16, sb*16+16), all 4 planes ----------------
    const int sb = blk - NXB;
    const int row = tid >> 6;                  // 0..15
    const int oc = tid & 63;                   // feature octet
    const int gr = sb * 16 + row;
    const bool valid = gr < NNODE;
    const float4* z4 = (const float4*)z;
    const float4* q4 = (const float4*)q;
    float4 za0, za1, zb0, zb1, zc0, zc1, zd0, zd1, qa, qb;
    float wi = 0.f, bi = 0.f;
    za0 = za1 = zb0 = zb1 = zc0 = zc1 = zd0 = zd1 = (float4){0,0,0,0};
    qa = qb = (float4){0,0,0,0};
    const int zi = gr * 128 + oc * 2;
    if (valid) {
      za0 = z4[zi];                 za1 = z4[zi + 1];
      zb0 = z4[NNODE*128 + zi];     zb1 = z4[NNODE*128 + zi + 1];
      zc0 = z4[2*NNODE*128 + zi];   zc1 = z4[2*NNODE*128 + zi + 1];
      zd0 = z4[3*NNODE*128 + zi];   zd1 = z4[3*NNODE*128 + zi + 1];
      qa  = q4[zi];                 qb  = q4[zi + 1];
      wi = W[gr]; bi = b[gr];
    }
    auto dot8 = [&](const float4& u0, const float4& u1) -> float {
      return tanhf(wi*u0.x + bi)*qa.x + tanhf(wi*u0.y + bi)*qa.y
           + tanhf(wi*u0.z + bi)*qa.z + tanhf(wi*u0.w + bi)*qa.w
           + tanhf(wi*u1.x + bi)*qb.x + tanhf(wi*u1.y + bi)*qb.y
           + tanhf(wi*u1.z + bi)*qb.z + tanhf(wi*u1.w + bi)*qb.w;
    };
    float sp0 = valid ? dot8(za0, za1) : 0.f;
    float sp1 = valid ? dot8(zb0, zb1) : 0.f;
    float sp2 = valid ? dot8(zc0, zc1) : 0.f;
    float sp3 = valid ? dot8(zd0, zd1) : 0.f;
#pragma unroll
    for (int m = 1; m < 64; m <<= 1) {
      sp0 += __shfl_xor(sp0, m); sp1 += __shfl_xor(sp1, m);
      sp2 += __shfl_xor(sp2, m); sp3 += __shfl_xor(sp3, m);
    }
    __shared__ float sred[16][4];
    if (oc == 0) {
      sred[row][0] = sp0; sred[row][1] = sp1;
      sred[row][2] = sp2; sred[row][3] = sp3;
    }
    __syncthreads();
    if (tid < 4) {
      float s = 0.f;
#pragma unroll
      for (int r = 0; r < 16; ++r) s += sred[r][tid];
      ws[WS_SPART + tid * 55 + sb] = s;        // raw sum over this tile's rows
    }
  } else {
    // ---------------- PACK: bf16 repack, coalesced source reads ----------------
    const int pb = blk - (NXB + MT);
    if (pb < 16) {
      const int s0 = pb * 16384;
#pragma unroll
      for (int it = 0; it < 16; ++it) {
        const int s = s0 + it * 1024 + tid;
        const int k = s >> 9, n = s & 511;
        const int t = (k >> 5) * 16384 + (n >> 4) * 512 + ((k >> 3) & 3) * 128
                    + (n & 15) * 8 + (k & 7);
        w1p[t] = f2bf(w1[(size_t)(512 + k) * 512 + n]);
      }
    } else {
      const int o0 = (pb - 16) * 16384;
#pragma unroll
      for (int it = 0; it < 16; ++it) {
        const int o = o0 + it * 1024 + tid;
        const int k = o >> 8, n = o & 255;
        const int t = (k >> 5) * 8192 + (n >> 4) * 512 + ((k >> 3) & 3) * 128
                    + (n & 15) * 8 + (k & 7);
        w2p[t] = f2bf(w2[(size_t)k * 256 + n]);
      }
    }
  }
}

// ============ k_mid (5 blocks x 1024 thr): c1 slice GEMVs + counter zero ============
// blk 0..3: c1p[bk][j] = sum_f (sum_p xhp[p][f] + xpb[f]) * w1[f,j] for f-slice bk
// blk 4   : zero completion counter.
// xhp is coherent via the kernel boundary — no spin, no acquire fence.
__global__ __launch_bounds__(1024) void k_mid(const float* __restrict__ xpb,
                                              const float* __restrict__ w1,
                                              const float* __restrict__ b1,
                                              float* __restrict__ ws) {
  const int tid = threadIdx.x;
  if (blockIdx.x == 4) {
    if (tid == 0) *(unsigned*)&ws[WS_CNT] = 0u;
    return;
  }
  const int bk = blockIdx.x;                   // f-slice [bk*128, bk*128+128)
  __shared__ float xh[128];
  __shared__ float redr[1024];
  __shared__ float4 redg[7][128];
  const int f = tid & 127;
  const int part = tid >> 7;                   // 0..7
  {
    float s = 0.f;
    for (int p = part; p < NXB; p += 8)        // 32 independent loads
      s += ws[WS_XHP + (size_t)p * 512 + bk * 128 + f];
    redr[tid] = s;
  }
  __syncthreads();
  if (tid < 128) {
    float t = xpb[bk * 128 + tid];
#pragma unroll
    for (int g = 0; g < 8; ++g) t += redr[g * 128 + tid];
    xh[tid] = t;
  }
  __syncthreads();
  const int j4 = tid & 127;
  const int fg = tid >> 7;                     // 0..7 (16 f each)
  float4 acc = {0.f, 0.f, 0.f, 0.f};
  const float4* w14 = (const float4*)w1;
#pragma unroll
  for (int ff = 0; ff < 16; ++ff) {
    const int fr = bk * 128 + fg * 16 + ff;
    const float xv = xh[fg * 16 + ff];
    const float4 wv = w14[(size_t)fr * 128 + j4];
    acc.x += xv * wv.x; acc.y += xv * wv.y; acc.z += xv * wv.z; acc.w += xv * wv.w;
  }
  if (fg) redg[fg - 1][j4] = acc;
  __syncthreads();
  if (!fg) {
#pragma unroll
    for (int g = 0; g < 7; ++g) {
      float4 t = redg[g][j4];
      acc.x += t.x; acc.y += t.y; acc.z += t.z; acc.w += t.w;
    }
    if (bk == 0) {
      acc.x += b1[j4 * 4 + 0]; acc.y += b1[j4 * 4 + 1];
      acc.z += b1[j4 * 4 + 2]; acc.w += b1[j4 * 4 + 3];
    }
    ((float4*)(ws + WS_C1P + (size_t)bk * 512))[j4] = acc;
  }
}

// ============ k_fused (55 blocks x 1024 thr): coef(redundant) -> emb -> E1 -> relu+c1 -> H2
//              -> rowdot -> v store -> (last block) loss
// All cross-kernel inputs (spart, c1p, w1p, w2p) coherent via kernel boundaries.
__global__ __launch_bounds__(1024) void k_fused(const float* __restrict__ z,
                                                float* __restrict__ ws,
                                                float* __restrict__ out,
                                                const short* __restrict__ w1p,
                                                const short* __restrict__ w2p,
                                                const float* __restrict__ b2,
                                                const float* __restrict__ w3,
                                                const float* __restrict__ b3) {
  __shared__ __align__(16) short embs[8192];   // [64 koct][16 m][8], swizzled
  __shared__ __align__(16) short h2a[8192];
  __shared__ float cs[512];
  __shared__ float rf0[1024], rf1[1024];
  __shared__ float vred[16][17];
  __shared__ float cf[4];
  __shared__ float svred[4];
  const int tid = threadIdx.x;
  const int r0 = blockIdx.x * 16;
  const int oc = tid & 63;                     // k-octet / lane
  const int row = tid >> 6;                    // 0..15 / wave
  const int gr = r0 + row;
  const bool valid = gr < NNODE;

  // ---- issue z loads early (latency hides under coef + cs) ----
  const float4* z4 = (const float4*)z;
  float4 za0, za1, zb0, zb1, zc0, zc1, zd0, zd1;
  za0 = za1 = zb0 = zb1 = zc0 = zc1 = zd0 = zd1 = (float4){0,0,0,0};
  const int zi = gr * 128 + oc * 2;
  if (valid) {
    za0 = z4[zi];                 za1 = z4[zi + 1];
    zb0 = z4[NNODE*128 + zi];     zb1 = z4[NNODE*128 + zi + 1];
    zc0 = z4[2*NNODE*128 + zi];   zc1 = z4[2*NNODE*128 + zi + 1];
    zd0 = z4[3*NNODE*128 + zi];   zd1 = z4[3*NNODE*128 + zi + 1];
  }

  // ---- cs: c1 = sum of 4 slice-partials ----
  if (tid < 512) {
    float a = 0.f;
#pragma unroll
    for (int k = 0; k < 4; ++k) a += ws[WS_C1P + k * 512 + tid];
    cs[tid] = a;
  }

  // ---- coef: waves 0..3 reduce one plane's 55 spart chunks, thread 0 softmaxes ----
  {
    const int w4 = tid >> 6;
    if (w4 < 4) {
      float v = (oc < 55) ? ws[WS_SPART + w4 * 55 + oc] : 0.f;
#pragma unroll
      for (int m = 1; m < 64; m <<= 1) v += __shfl_xor(v, m);
      if (oc == 0) svred[w4] = v;
    }
  }
  __syncthreads();
  if (tid == 0) {
    float sv[NMETA], sum = 0.f;
#pragma unroll
    for (int p = 0; p < NMETA; ++p) { sv[p] = svred[p] / (float)NNODE; sum += sv[p]; }
    float m = -1e30f;
#pragma unroll
    for (int p = 0; p < NMETA; ++p) { sv[p] = sv[p] / sum; m = fmaxf(m, sv[p]); }
    float es = 0.f;
#pragma unroll
    for (int p = 0; p < NMETA; ++p) { sv[p] = expf(sv[p] - m); es += sv[p]; }
#pragma unroll
    for (int p = 0; p < NMETA; ++p) cf[p] = 1.f + sv[p] / es;
  }
  __syncthreads();
  const float c0 = cf[0], c1c = cf[1], c2 = cf[2], c3 = cf[3];

  // ---- emb from regs -> out (fp32) + embs (bf16 A-fragment) ----
  {
    const int slot = oc * 16 + (row ^ (oc & 15));
    v8s h;
    if (valid) {
      float4 r0v, r1v;
      r0v.x = c0*za0.x + c1c*zb0.x + c2*zc0.x + c3*zd0.x;
      r0v.y = c0*za0.y + c1c*zb0.y + c2*zc0.y + c3*zd0.y;
      r0v.z = c0*za0.z + c1c*zb0.z + c2*zc0.z + c3*zd0.z;
      r0v.w = c0*za0.w + c1c*zb0.w + c2*zc0.w + c3*zd0.w;
      r1v.x = c0*za1.x + c1c*zb1.x + c2*zc1.x + c3*zd1.x;
      r1v.y = c0*za1.y + c1c*zb1.y + c2*zc1.y + c3*zd1.y;
      r1v.z = c0*za1.z + c1c*zb1.z + c2*zc1.z + c3*zd1.z;
      r1v.w = c0*za1.w + c1c*zb1.w + c2*zc1.w + c3*zd1.w;
      ((float4*)out)[zi] = r0v;
      ((float4*)out)[zi + 1] = r1v;
      h[0] = f2bf(r0v.x); h[1] = f2bf(r0v.y); h[2] = f2bf(r0v.z); h[3] = f2bf(r0v.w);
      h[4] = f2bf(r1v.x); h[5] = f2bf(r1v.y); h[6] = f2bf(r1v.z); h[7] = f2bf(r1v.w);
    } else {
      h = (v8s){0,0,0,0,0,0,0,0};
    }
    *(v8s*)(embs + slot * 8) = h;
  }
  __syncthreads();

  // ---- E1: wave w (0..15) -> 2 n-tiles (cols w*32..w*32+31) ----
  const int lane = tid & 63, w = tid >> 6;
  const int n15 = lane & 15, quad = lane >> 4;
  v4f e[2];
#pragma unroll
  for (int ct = 0; ct < 2; ++ct) e[ct] = (v4f){0.f, 0.f, 0.f, 0.f};
#pragma unroll
  for (int kb = 0; kb < 16; ++kb) {
    const int koct = kb * 4 + quad;
    v8s a = *(const v8s*)(embs + (koct * 16 + (n15 ^ (koct & 15))) * 8);
    const short* B = w1p + kb * 16384 + w * 1024 + quad * 128 + n15 * 8;
#pragma unroll
    for (int ct = 0; ct < 2; ++ct) {
      v8s bb = *(const v8s*)(B + ct * 512);
      e[ct] = __builtin_amdgcn_mfma_f32_16x16x32_bf16(a, bb, e[ct], 0, 0, 0);
    }
  }
#pragma unroll
  for (int ct = 0; ct < 2; ++ct) {
    const int col = w * 32 + ct * 16 + n15;
    const int koct = col >> 3, j = col & 7;
#pragma unroll
    for (int r = 0; r < 4; ++r) {
      const int m = quad * 4 + r;
      h2a[(koct * 16 + (m ^ (koct & 15))) * 8 + j] = f2bf(fmaxf(e[ct][r] + cs[col], 0.f));
    }
  }
  __syncthreads();

  // ---- H2: wave w -> 1 n-tile (cols w*16..w*16+15); fused rowdot ----
  v4f g = (v4f){0.f, 0.f, 0.f, 0.f};
#pragma unroll
  for (int kb = 0; kb < 16; ++kb) {
    const int koct = kb * 4 + quad;
    v8s a = *(const v8s*)(h2a + (koct * 16 + (n15 ^ (koct & 15))) * 8);
    v8s bb = *(const v8s*)(w2p + kb * 8192 + w * 512 + quad * 128 + n15 * 8);
    g = __builtin_amdgcn_mfma_f32_16x16x32_bf16(a, bb, g, 0, 0, 0);
  }
  {
    const int col = w * 16 + n15;
    const float b2v = b2[col], w3v = w3[col];
#pragma unroll
    for (int r = 0; r < 4; ++r) {
      float s = fmaxf(g[r] + b2v, 0.f) * w3v;
      s += __shfl_xor(s, 1);
      s += __shfl_xor(s, 2);
      s += __shfl_xor(s, 4);
      s += __shfl_xor(s, 8);
      if (n15 == 0) vred[quad * 4 + r][w] = s;
    }
  }
  __syncthreads();
  if (tid < 16) {
    float acc = 0.f;
#pragma unroll
    for (int ww = 0; ww < 16; ++ww) acc += vred[tid][ww];
    const int grow = r0 + tid;
    if (grow < NNODE) ws[WS_V + grow] = acc;   // single writer per row
  }

  // ---- last-block final loss ----
  __shared__ unsigned last;
  __syncthreads();
  if (tid == 0) {
    __threadfence();                           // release v stores before counting
    unsigned old = atomicAdd((unsigned int*)&ws[WS_CNT], 1u);
    last = (old == MT - 1) ? 1u : 0u;
  }
  __syncthreads();
  if (last) {
    __builtin_amdgcn_fence(__ATOMIC_ACQUIRE, "agent");   // see other blocks' v stores
    const float bias = b3[0];
    float s0 = 0.f, s1 = 0.f;
    for (int i = tid; i < NNODE; i += 1024) {
      float xv = ws[WS_V + i] + bias;
      s0 += xv;
      s1 += expf(xv);
    }
    rf0[tid] = s0; rf1[tid] = s1;
    __syncthreads();
    for (int s = 512; s > 0; s >>= 1) {
      if (tid < s) { rf0[tid] += rf0[tid + s]; rf1[tid] += rf1[tid + s]; }
      __syncthreads();
    }
    if (tid == 0) {
      float m0 = rf0[0] / (float)NNODE;
      float m1 = rf1[0] / (float)NNODE;
      float mi = m0 - logf(m1 + 1e-8f);
      out[ZPLANE] = fmaxf(mi, 0.f) + 0.1f;     // sum(softmax)==1 -> gamma term = 0.1
    }
  }
}

extern "C" void kernel_launch(void* const* d_in, const int* in_sizes, int n_in,
                              void* d_out, int out_size, void* d_ws, size_t ws_size,
                              hipStream_t stream) {
  const float* z   = (const float*)d_in[0];
  const float* x   = (const float*)d_in[1];
  const float* W   = (const float*)d_in[2];
  const float* b   = (const float*)d_in[3];
  const float* q   = (const float*)d_in[4];
  const float* xpw = (const float*)d_in[5];
  const float* xpb = (const float*)d_in[6];
  const float* w1  = (const float*)d_in[7];
  const float* b1  = (const float*)d_in[8];
  const float* w2  = (const float*)d_in[9];
  const float* b2  = (const float*)d_in[10];
  const float* w3  = (const float*)d_in[11];
  const float* b3  = (const float*)d_in[12];
  // d_in[13] (perm) unused: xh identical per row => permutation invariant under mean(exp(.)).
  float* out = (float*)d_out;
  float* ws  = (float*)d_ws;

  short* w1p = (short*)(ws + WS_W1P);
  short* w2p = (short*)(ws + WS_W2P);

  k_front<<<NXB + MT + 20, 1024, 0, stream>>>(x, xpw, w1, w2, z, W, b, q,
                                              ws, w1p, w2p);
  k_mid<<<5, 1024, 0, stream>>>(xpb, w1, b1, ws);
  k_fused<<<MT, 1024, 0, stream>>>(z, ws, out, w1p, w2p, b2, w3, b3);
}